// Round 5
// baseline (277.033 us; speedup 1.0000x reference)
//
#include <hip/hip_runtime.h>
#include <math.h>

#define DIN 1024
#define DH 512
#define DATT 256
#define CNUM 10
#define NCLS 4
#define ROWS 32            // point rows per k_phi block

typedef __attribute__((ext_vector_type(8))) short bf16x8;
typedef __attribute__((ext_vector_type(4))) float f32x4;
typedef unsigned short ushort_t;
typedef unsigned int uint_t;

__device__ inline ushort_t f2bf(float f) {
    uint_t u = __float_as_uint(f);
    u += 0x7FFF + ((u >> 16) & 1);   // RNE
    return (ushort_t)(u >> 16);
}

// async global->LDS, 16B per lane. LDS dst must be wave-uniform base + lane*16.
__device__ inline void gl_lds16(const void* g, void* l) {
    __builtin_amdgcn_global_load_lds(
        (const __attribute__((address_space(1))) unsigned int*)g,
        (__attribute__((address_space(3))) unsigned int*)l, 16, 0, 0);
}

// ---------------- bucketing: hist+scan+scatter+init in ONE block ----------------

__global__ __launch_bounds__(1024) void k_bucket(
    const int* __restrict__ cid, int n, const float* __restrict__ bc,
    int* __restrict__ counts_g, int* __restrict__ offsets_g, int* __restrict__ tile_off_g,
    int* __restrict__ bucket, float* __restrict__ pooled, float* __restrict__ a_logit)
{
    __shared__ int h[CNUM], off[CNUM + 1], cur[CNUM], toff[CNUM + 1];
    int t = threadIdx.x;
    int lane = t & 63;
    if (t < CNUM) { h[t] = 0; cur[t] = 0; }
    __syncthreads();

    for (int i = t; i < n; i += 1024) {
        int c = cid[i];
        #pragma unroll
        for (int cc = 0; cc < CNUM; cc++) {
            unsigned long long mask = __ballot(c == cc);
            if (mask == 0ull) continue;
            int leader = __ffsll(mask) - 1;
            if (lane == leader) atomicAdd(&h[cc], __popcll(mask));
        }
    }
    __syncthreads();
    if (t == 0) {
        int a = 0, tt = 0;
        for (int c = 0; c < CNUM; c++) {
            off[c] = a; toff[c] = tt;
            a += h[c]; tt += (h[c] + ROWS - 1) / ROWS;
        }
        off[CNUM] = a; toff[CNUM] = tt;
    }
    __syncthreads();
    if (t < CNUM) counts_g[t] = h[t];
    if (t <= CNUM) { offsets_g[t] = off[t]; tile_off_g[t] = toff[t]; }
    if (t < CNUM) a_logit[t] = bc[0];

    for (int i = t; i < n; i += 1024) {
        int c = cid[i];
        #pragma unroll
        for (int cc = 0; cc < CNUM; cc++) {
            unsigned long long mask = __ballot(c == cc);
            if (mask == 0ull) continue;
            int leader = __ffsll(mask) - 1;
            int basep = 0;
            if (lane == leader) basep = atomicAdd(&cur[cc], __popcll(mask));
            basep = __shfl(basep, leader, 64);
            if (c == cc) {
                int rank = __popcll(mask & ((1ull << lane) - 1ull));
                bucket[off[cc] + basep + rank] = i;
            }
        }
    }
    for (int i = t; i < CNUM * DH; i += 1024) pooled[i] = 0.f;
}

// ---------------- weight transpose+cast: W[c][K][N] fp32 -> Wt[c][N][K] bf16 ----------------

__global__ __launch_bounds__(256) void k_castw(
    const float* __restrict__ W1, const float* __restrict__ W2,
    ushort_t* __restrict__ W1t, ushort_t* __restrict__ W2t)
{
    __shared__ float tile[64][65];
    int z = blockIdx.z;
    const float* src; ushort_t* dst; int K;
    if (z < CNUM) { K = DIN; src = W1 + (size_t)z * K * DH; dst = W1t + (size_t)z * DH * K; }
    else          { K = DH;  src = W2 + (size_t)(z - CNUM) * K * DH; dst = W2t + (size_t)(z - CNUM) * DH * K; }
    int k0 = blockIdx.x * 64;
    if (k0 >= K) return;
    int n0 = blockIdx.y * 64;
    int t = threadIdx.x;
    int rr = t >> 4;
    int cc = (t & 15) * 4;
    #pragma unroll
    for (int i = 0; i < 4; i++) {
        int row = rr + 16 * i;
        float4 v = *(const float4*)(src + (size_t)(k0 + row) * DH + n0 + cc);
        tile[row][cc + 0] = v.x; tile[row][cc + 1] = v.y;
        tile[row][cc + 2] = v.z; tile[row][cc + 3] = v.w;
    }
    __syncthreads();
    #pragma unroll
    for (int i = 0; i < 4; i++) {
        int nrow = rr + 16 * i;
        ushort4 o = make_ushort4(f2bf(tile[cc + 0][nrow]), f2bf(tile[cc + 1][nrow]),
                                 f2bf(tile[cc + 2][nrow]), f2bf(tile[cc + 3][nrow]));
        *(ushort4*)(dst + (size_t)(n0 + nrow) * K + k0 + cc) = o;
    }
}

// ---------------- fused phi: gather/cast + GEMM1 + GEMM2 + pooled sums ----------------
// One block = 32 point-rows of one cluster. H1 lives entirely in LDS (chunked
// [k/32][row][k%32] layout = same conflict-free pattern as the staging tiles).
// 4 waves: wave w owns cols [64w,64w+64) of each 256-col pass.
// A frag: lane m reads rows (16mf+m), k = quad*8..+7 (b128, k-contiguous).
// C/D: col = lane&15, row = quad*4 + reg  [m89/m91].

__global__ __launch_bounds__(256, 1) void k_phi(
    const float* __restrict__ x, const int* __restrict__ bucket,
    const ushort_t* __restrict__ W1t, const ushort_t* __restrict__ W2t,
    const float* __restrict__ b1, const float* __restrict__ b2,
    const int* __restrict__ offsets, const int* __restrict__ counts,
    const int* __restrict__ tile_off,
    float* __restrict__ pooled)
{
    __shared__ ushort_t As[ROWS][32];          // 2 KB
    __shared__ ushort_t Bs[256][32];           // 16 KB
    __shared__ ushort_t H1s[16][ROWS][32];     // 32 KB: [k/32][row][k%32]

    int tx = blockIdx.x;
    if (tx >= tile_off[CNUM]) return;
    int c = 0;
    while (tx >= tile_off[c + 1]) c++;
    int m0 = (tx - tile_off[c]) * ROWS;
    int base = offsets[c], cnt = counts[c];

    int t = threadIdx.x, lane = t & 63;
    int w = t >> 6;
    int m = lane & 15, quad = lane >> 4;

    // A gather source (fp32, bucket-indirect)
    int ar = t >> 3;               // 0..31
    int akc = (t & 7) * 4;         // 0,4,...,28
    int arow = m0 + ar; if (arow > cnt - 1) arow = cnt - 1;
    const float* aPtr = x + (size_t)bucket[base + arow] * DIN + akc;

    // B staging (global_load_lds): dst = Bs + 16*t (+4096*i), wave-uniform+lane*16
    char* bsDst = (char*)&Bs[0][0] + 16 * t;
    int bRow = t >> 2;             // 0..63
    int bKc = (t & 3) * 8;

    const ushort_t* aF0 = &As[m][quad * 8];
    const ushort_t* aF1 = &As[16 + m][quad * 8];
    const ushort_t* bF  = &Bs[64 * w + m][quad * 8];

    f32x4 acc[2][4];

    // ---------------- layer 1: H1 = relu(x @ W1 + b1) -> LDS ----------------
    #pragma unroll
    for (int p = 0; p < 2; p++) {
        #pragma unroll
        for (int mf = 0; mf < 2; mf++)
            #pragma unroll
            for (int nf = 0; nf < 4; nf++) acc[mf][nf] = (f32x4)(0.f);

        const ushort_t* wp = W1t + ((size_t)c * DH + p * 256 + bRow) * DIN + bKc;

        for (int k0 = 0; k0 < DIN; k0 += 32) {
            __syncthreads();
            float4 av = *(const float4*)(aPtr + k0);
            *(ushort4*)&As[ar][akc] =
                make_ushort4(f2bf(av.x), f2bf(av.y), f2bf(av.z), f2bf(av.w));
            #pragma unroll
            for (int i = 0; i < 4; i++)
                gl_lds16(wp + k0 + (size_t)(64 * i) * DIN, bsDst + 4096 * i);
            __syncthreads();

            bf16x8 a0 = *(const bf16x8*)aF0;
            bf16x8 a1 = *(const bf16x8*)aF1;
            bf16x8 b[4];
            #pragma unroll
            for (int nf = 0; nf < 4; nf++) b[nf] = *(const bf16x8*)(bF + nf * 512);
            #pragma unroll
            for (int nf = 0; nf < 4; nf++) {
                acc[0][nf] = __builtin_amdgcn_mfma_f32_16x16x32_bf16(a0, b[nf], acc[0][nf], 0, 0, 0);
                acc[1][nf] = __builtin_amdgcn_mfma_f32_16x16x32_bf16(a1, b[nf], acc[1][nf], 0, 0, 0);
            }
        }

        // epilogue: bias+relu, write into chunked H1s
        #pragma unroll
        for (int nf = 0; nf < 4; nf++) {
            int colL = 64 * w + 16 * nf + m;
            int col = p * 256 + colL;
            float bv = b1[c * DH + col];
            int chunk = p * 8 + (colL >> 5);
            int ck = colL & 31;
            #pragma unroll
            for (int mf = 0; mf < 2; mf++)
                #pragma unroll
                for (int r = 0; r < 4; r++)
                    H1s[chunk][16 * mf + quad * 4 + r][ck] =
                        f2bf(fmaxf(acc[mf][nf][r] + bv, 0.f));
        }
    }

    // ---------------- layer 2: pooled += relu(H1 @ W2 + b2), masked ----------------
    #pragma unroll
    for (int p = 0; p < 2; p++) {
        #pragma unroll
        for (int mf = 0; mf < 2; mf++)
            #pragma unroll
            for (int nf = 0; nf < 4; nf++) acc[mf][nf] = (f32x4)(0.f);

        const ushort_t* wp = W2t + ((size_t)c * DH + p * 256 + bRow) * DH + bKc;

        for (int k0 = 0; k0 < DH; k0 += 32) {
            __syncthreads();
            #pragma unroll
            for (int i = 0; i < 4; i++)
                gl_lds16(wp + k0 + (size_t)(64 * i) * DH, bsDst + 4096 * i);
            __syncthreads();

            const ushort_t* h = &H1s[k0 >> 5][0][0];
            bf16x8 a0 = *(const bf16x8*)(h + m * 32 + quad * 8);
            bf16x8 a1 = *(const bf16x8*)(h + (16 + m) * 32 + quad * 8);
            bf16x8 b[4];
            #pragma unroll
            for (int nf = 0; nf < 4; nf++) b[nf] = *(const bf16x8*)(bF + nf * 512);
            #pragma unroll
            for (int nf = 0; nf < 4; nf++) {
                acc[0][nf] = __builtin_amdgcn_mfma_f32_16x16x32_bf16(a0, b[nf], acc[0][nf], 0, 0, 0);
                acc[1][nf] = __builtin_amdgcn_mfma_f32_16x16x32_bf16(a1, b[nf], acc[1][nf], 0, 0, 0);
            }
        }

        #pragma unroll
        for (int nf = 0; nf < 4; nf++) {
            int col = p * 256 + 64 * w + 16 * nf + m;
            float bv = b2[c * DH + col];
            float s = 0.f;
            #pragma unroll
            for (int mf = 0; mf < 2; mf++)
                #pragma unroll
                for (int r = 0; r < 4; r++) {
                    int row = m0 + 16 * mf + quad * 4 + r;
                    if (row < cnt) s += fmaxf(acc[mf][nf][r] + bv, 0.f);
                }
            s += __shfl_xor(s, 16);
            s += __shfl_xor(s, 32);
            if (quad == 0) atomicAdd(&pooled[c * DH + col], s);
        }
    }
}

// ---------------- fp32 fallback GEMMs (round-1 proven) ----------------

#define MT 64
#define NT 128
#define KT 32

__global__ __launch_bounds__(256) void k_gemm1(
    const float* __restrict__ x, const float* __restrict__ W1, const float* __restrict__ b1,
    const int* __restrict__ bucket, const int* __restrict__ offsets, const int* __restrict__ counts,
    float* __restrict__ H1)
{
    int c = blockIdx.z;
    int cnt = counts[c];
    int m0 = blockIdx.x * MT;
    if (m0 >= cnt) return;
    int rows = min(MT, cnt - m0);
    int n0 = blockIdx.y * NT;
    int base = offsets[c];

    __shared__ float As[KT][MT + 4];
    __shared__ float Bs[KT][NT];

    int t = threadIdx.x;
    int tr = t >> 4;
    int tc = t & 15;
    int lr = t >> 2;
    int lk = (t & 3) * 8;
    const float* xrow = nullptr;
    if (lr < rows) xrow = x + (size_t)bucket[base + m0 + lr] * DIN;

    float acc[4][8];
    #pragma unroll
    for (int i = 0; i < 4; i++)
        #pragma unroll
        for (int j = 0; j < 8; j++) acc[i][j] = 0.f;

    const float* Wp = W1 + (size_t)c * DIN * DH + n0;

    for (int k0 = 0; k0 < DIN; k0 += KT) {
        __syncthreads();
        if (xrow) {
            float4 v0 = *(const float4*)(xrow + k0 + lk);
            float4 v1 = *(const float4*)(xrow + k0 + lk + 4);
            As[lk + 0][lr] = v0.x; As[lk + 1][lr] = v0.y;
            As[lk + 2][lr] = v0.z; As[lk + 3][lr] = v0.w;
            As[lk + 4][lr] = v1.x; As[lk + 5][lr] = v1.y;
            As[lk + 6][lr] = v1.z; As[lk + 7][lr] = v1.w;
        } else {
            #pragma unroll
            for (int i = 0; i < 8; i++) As[lk + i][lr] = 0.f;
        }
        #pragma unroll
        for (int i = 0; i < 4; i++) {
            int idx = i * 256 + t;
            int kk = idx >> 5;
            int cv = idx & 31;
            *(float4*)&Bs[kk][cv * 4] = *(const float4*)(Wp + (size_t)(k0 + kk) * DH + cv * 4);
        }
        __syncthreads();
        #pragma unroll
        for (int k = 0; k < KT; k++) {
            float4 av  = *(const float4*)&As[k][4 * tr];
            float4 bv0 = *(const float4*)&Bs[k][4 * tc];
            float4 bv1 = *(const float4*)&Bs[k][64 + 4 * tc];
            float a[4] = {av.x, av.y, av.z, av.w};
            float b[8] = {bv0.x, bv0.y, bv0.z, bv0.w, bv1.x, bv1.y, bv1.z, bv1.w};
            #pragma unroll
            for (int i = 0; i < 4; i++)
                #pragma unroll
                for (int j = 0; j < 8; j++)
                    acc[i][j] = fmaf(a[i], b[j], acc[i][j]);
        }
    }

    #pragma unroll
    for (int i = 0; i < 4; i++) {
        int r = 4 * tr + i;
        if (r < rows) {
            size_t grow = (size_t)(base + m0 + r) * DH;
            #pragma unroll
            for (int j = 0; j < 8; j++) {
                int cidx = (j < 4) ? (4 * tc + j) : (64 + 4 * tc + (j - 4));
                int col = n0 + cidx;
                float v = acc[i][j] + b1[c * DH + col];
                H1[grow + col] = fmaxf(v, 0.f);
            }
        }
    }
}

__global__ __launch_bounds__(256) void k_gemm2(
    const float* __restrict__ H1, const float* __restrict__ W2, const float* __restrict__ b2,
    const int* __restrict__ offsets, const int* __restrict__ counts,
    float* __restrict__ pooled)
{
    int c = blockIdx.z;
    int cnt = counts[c];
    int m0 = blockIdx.x * MT;
    if (m0 >= cnt) return;
    int rows = min(MT, cnt - m0);
    int n0 = blockIdx.y * NT;
    int base = offsets[c];

    __shared__ float As[KT][MT + 4];
    __shared__ float Bs[KT][NT];
    __shared__ float red[16][NT];

    int t = threadIdx.x;
    int tr = t >> 4;
    int tc = t & 15;
    int lr = t >> 2;
    int lk = (t & 3) * 8;
    const float* arow = (lr < rows) ? (H1 + (size_t)(base + m0 + lr) * DH) : nullptr;

    float acc[4][8];
    #pragma unroll
    for (int i = 0; i < 4; i++)
        #pragma unroll
        for (int j = 0; j < 8; j++) acc[i][j] = 0.f;

    const float* Wp = W2 + (size_t)c * DH * DH + n0;

    for (int k0 = 0; k0 < DH; k0 += KT) {
        __syncthreads();
        if (arow) {
            float4 v0 = *(const float4*)(arow + k0 + lk);
            float4 v1 = *(const float4*)(arow + k0 + lk + 4);
            As[lk + 0][lr] = v0.x; As[lk + 1][lr] = v0.y;
            As[lk + 2][lr] = v0.z; As[lk + 3][lr] = v0.w;
            As[lk + 4][lr] = v1.x; As[lk + 5][lr] = v1.y;
            As[lk + 6][lr] = v1.z; As[lk + 7][lr] = v1.w;
        } else {
            #pragma unroll
            for (int i = 0; i < 8; i++) As[lk + i][lr] = 0.f;
        }
        #pragma unroll
        for (int i = 0; i < 4; i++) {
            int idx = i * 256 + t;
            int kk = idx >> 5;
            int cv = idx & 31;
            *(float4*)&Bs[kk][cv * 4] = *(const float4*)(Wp + (size_t)(k0 + kk) * DH + cv * 4);
        }
        __syncthreads();
        #pragma unroll
        for (int k = 0; k < KT; k++) {
            float4 av  = *(const float4*)&As[k][4 * tr];
            float4 bv0 = *(const float4*)&Bs[k][4 * tc];
            float4 bv1 = *(const float4*)&Bs[k][64 + 4 * tc];
            float a[4] = {av.x, av.y, av.z, av.w};
            float b[8] = {bv0.x, bv0.y, bv0.z, bv0.w, bv1.x, bv1.y, bv1.z, bv1.w};
            #pragma unroll
            for (int i = 0; i < 4; i++)
                #pragma unroll
                for (int j = 0; j < 8; j++)
                    acc[i][j] = fmaf(a[i], b[j], acc[i][j]);
        }
    }

    __syncthreads();
    #pragma unroll
    for (int j = 0; j < 8; j++) {
        int cidx = (j < 4) ? (4 * tc + j) : (64 + 4 * tc + (j - 4));
        float bias = b2[c * DH + n0 + cidx];
        float s = 0.f;
        #pragma unroll
        for (int i = 0; i < 4; i++) {
            if (4 * tr + i < rows) s += fmaxf(acc[i][j] + bias, 0.f);
        }
        red[tr][cidx] = s;
    }
    __syncthreads();
    if (t < NT) {
        float s = 0.f;
        #pragma unroll
        for (int r = 0; r < 16; r++) s += red[r][t];
        atomicAdd(&pooled[c * DH + n0 + t], s);
    }
}

// ---------------- parallel epilogue ----------------

__global__ __launch_bounds__(256) void k_fc2(
    const float* __restrict__ pooled, const int* __restrict__ counts,
    const float* __restrict__ Wfc, const float* __restrict__ bfc,
    float* __restrict__ hfc)
{
    int c = blockIdx.x;
    int c0 = blockIdx.y * 64;
    __shared__ float ps[DH];
    __shared__ float red[4][64];
    int t = threadIdx.x;
    float cnt = fmaxf((float)counts[c], 1.f);
    ps[t] = pooled[c * DH + t] / cnt;
    ps[t + 256] = pooled[c * DH + t + 256] / cnt;
    __syncthreads();
    int col = c0 + (t & 63);
    int ks = t >> 6;
    float acc = 0.f;
    #pragma unroll 8
    for (int k = ks * 128; k < ks * 128 + 128; k++)
        acc = fmaf(ps[k], Wfc[(size_t)k * DH + col], acc);
    red[ks][t & 63] = acc;
    __syncthreads();
    if (t < 64) {
        float v = red[0][t] + red[1][t] + red[2][t] + red[3][t] + bfc[c0 + t];
        hfc[c * DH + c0 + t] = fmaxf(v, 0.f);
    }
}

__global__ __launch_bounds__(256) void k_gate2(
    const float* __restrict__ hfc,
    const float* __restrict__ Wa, const float* __restrict__ ba,
    const float* __restrict__ Wb, const float* __restrict__ bb,
    const float* __restrict__ Wc,
    float* __restrict__ a_logit)
{
    int c = blockIdx.x;
    int d0 = blockIdx.y * 64;
    __shared__ float hf[DH];
    __shared__ float ra[4][64], rb[4][64];
    int t = threadIdx.x;
    hf[t] = hfc[c * DH + t];
    hf[t + 256] = hfc[c * DH + t + 256];
    __syncthreads();
    int d = d0 + (t & 63);
    int ks = t >> 6;
    float ga = 0.f, gb = 0.f;
    #pragma unroll 8
    for (int k = ks * 128; k < ks * 128 + 128; k++) {
        float h = hf[k];
        ga = fmaf(h, Wa[(size_t)k * DATT + d], ga);
        gb = fmaf(h, Wb[(size_t)k * DATT + d], gb);
    }
    ra[ks][t & 63] = ga;
    rb[ks][t & 63] = gb;
    __syncthreads();
    if (t < 64) {
        float sa = ra[0][t] + ra[1][t] + ra[2][t] + ra[3][t] + ba[d0 + t];
        float sb = rb[0][t] + rb[1][t] + rb[2][t] + rb[3][t] + bb[d0 + t];
        float g = tanhf(sa) * (1.f / (1.f + expf(-sb)));
        float p = g * Wc[d0 + t];
        #pragma unroll
        for (int off = 32; off >= 1; off >>= 1) p += __shfl_down(p, off, 64);
        if (t == 0) atomicAdd(&a_logit[c], p);
    }
}

__global__ __launch_bounds__(1024) void k_final(
    const float* __restrict__ hfc, const float* __restrict__ a_logit,
    const float* __restrict__ Wr, const float* __restrict__ br,
    const float* __restrict__ Wcls, const float* __restrict__ bcls,
    float* __restrict__ out)
{
    int t = threadIdx.x;
    __shared__ float hp[DH];
    __shared__ float r1[4][DATT];
    __shared__ float hr[DATT];
    __shared__ float wred[4][NCLS];

    float al[CNUM];
    float m = -1e30f;
    #pragma unroll
    for (int c = 0; c < CNUM; c++) { al[c] = a_logit[c]; m = fmaxf(m, al[c]); }
    float s = 0.f;
    #pragma unroll
    for (int c = 0; c < CNUM; c++) { al[c] = expf(al[c] - m); s += al[c]; }
    float inv = 1.f / s;

    if (t < DH) {
        float v = 0.f;
        #pragma unroll
        for (int c = 0; c < CNUM; c++) v = fmaf(al[c] * inv, hfc[c * DH + t], v);
        hp[t] = v;
    }
    __syncthreads();

    int d = t & 255;
    int ks = t >> 8;
    float acc = 0.f;
    #pragma unroll 8
    for (int k = ks * 128; k < ks * 128 + 128; k++)
        acc = fmaf(hp[k], Wr[(size_t)k * DATT + d], acc);
    r1[ks][d] = acc;
    __syncthreads();
    if (t < DATT)
        hr[t] = fmaxf(r1[0][t] + r1[1][t] + r1[2][t] + r1[3][t] + br[t], 0.f);
    __syncthreads();

    if (t < 256) {
        float h = hr[t];
        #pragma unroll
        for (int cls = 0; cls < NCLS; cls++) {
            float p = h * Wcls[(size_t)t * NCLS + cls];
            #pragma unroll
            for (int off = 32; off >= 1; off >>= 1) p += __shfl_down(p, off, 64);
            if ((t & 63) == 0) wred[t >> 6][cls] = p;
        }
    }
    __syncthreads();
    if (t == 0) {
        float lg[NCLS];
        #pragma unroll
        for (int cls = 0; cls < NCLS; cls++)
            lg[cls] = bcls[cls] + wred[0][cls] + wred[1][cls] + wred[2][cls] + wred[3][cls];
        float mm = lg[0];
        #pragma unroll
        for (int i = 1; i < NCLS; i++) mm = fmaxf(mm, lg[i]);
        float ss = 0.f, pr[NCLS];
        #pragma unroll
        for (int i = 0; i < NCLS; i++) { pr[i] = expf(lg[i] - mm); ss += pr[i]; }
        int am = 0; float best = lg[0];
        #pragma unroll
        for (int i = 1; i < NCLS; i++) if (lg[i] > best) { best = lg[i]; am = i; }
        #pragma unroll
        for (int i = 0; i < NCLS; i++) out[i] = lg[i];
        #pragma unroll
        for (int i = 0; i < NCLS; i++) out[4 + i] = pr[i] / ss;
        out[8] = (float)am;
    }
}

// ---------------- launcher ----------------

extern "C" void kernel_launch(void* const* d_in, const int* in_sizes, int n_in,
                              void* d_out, int out_size, void* d_ws, size_t ws_size,
                              hipStream_t stream) {
    (void)n_in; (void)out_size;
    const float* x    = (const float*)d_in[0];
    const int*   cid  = (const int*)d_in[1];
    const float* W1   = (const float*)d_in[2];
    const float* b1   = (const float*)d_in[3];
    const float* W2   = (const float*)d_in[4];
    const float* b2   = (const float*)d_in[5];
    const float* Wfc  = (const float*)d_in[6];
    const float* bfc  = (const float*)d_in[7];
    const float* Wa   = (const float*)d_in[8];
    const float* ba   = (const float*)d_in[9];
    const float* Wb   = (const float*)d_in[10];
    const float* bb   = (const float*)d_in[11];
    const float* Wc   = (const float*)d_in[12];
    const float* bc   = (const float*)d_in[13];
    const float* Wr   = (const float*)d_in[14];
    const float* br   = (const float*)d_in[15];
    const float* Wcls = (const float*)d_in[16];
    const float* bcls = (const float*)d_in[17];
    float* out = (float*)d_out;
    float* ws  = (float*)d_ws;

    int n = in_sizes[1];

    float* pooled   = ws + 0;                 // 5120
    int*   counts   = (int*)(ws + 5120);      // 16
    int*   offsets  = (int*)(ws + 5136);      // 16
    int*   tile_off = (int*)(ws + 5152);      // 16
    float* a_logit  = ws + 5168;              // 16
    float* hfc      = ws + 5184;              // 5120 -> ends 10304
    int*   bucket   = (int*)(ws + 10304);     // n

    size_t big0 = (((size_t)(10304 + n) * 4) + 255) & ~(size_t)255;
    size_t w1t_bytes = (size_t)CNUM * DH * DIN * 2;
    size_t w2t_bytes = (size_t)CNUM * DH * DH * 2;
    size_t need = big0 + w1t_bytes + w2t_bytes;

    k_bucket<<<1, 1024, 0, stream>>>(cid, n, bc, counts, offsets, tile_off, bucket, pooled, a_logit);

    if (ws_size >= need) {
        // ---------- fused MFMA fast path ----------
        ushort_t* W1t = (ushort_t*)((char*)d_ws + big0);
        ushort_t* W2t = (ushort_t*)((char*)d_ws + big0 + w1t_bytes);

        k_castw<<<dim3(DIN / 64, DH / 64, 2 * CNUM), 256, 0, stream>>>(W1, W2, W1t, W2t);

        int maxt = (n + ROWS - 1) / ROWS + CNUM;
        k_phi<<<maxt, 256, 0, stream>>>(x, bucket, W1t, W2t, b1, b2,
                                        offsets, counts, tile_off, pooled);
    } else {
        // ---------- fp32 fallback ----------
        float* H1f = ws + ((10304 + n + 31) & ~31);
        dim3 gg((n + MT - 1) / MT, DH / NT, CNUM);
        k_gemm1<<<gg, 256, 0, stream>>>(x, W1, b1, bucket, offsets, counts, H1f);
        k_gemm2<<<gg, 256, 0, stream>>>(H1f, W2, b2, offsets, counts, pooled);
    }

    k_fc2<<<dim3(CNUM, 8), 256, 0, stream>>>(pooled, counts, Wfc, bfc, hfc);
    k_gate2<<<dim3(CNUM, 4), 256, 0, stream>>>(hfc, Wa, ba, Wb, bb, Wc, a_logit);
    k_final<<<1, 1024, 0, stream>>>(hfc, a_logit, Wr, br, Wcls, bcls, out);
}